// Round 1
// baseline (651.550 us; speedup 1.0000x reference)
//
#include <hip/hip_runtime.h>
#include <math.h>

#define B 8
#define D 256
#define N_LIVE 10000
#define K_NEW 32
#define KC 10032
#define NS 100
#define NROW 101            // 100 bootstrap rows + 1 plain-softmax row (the score)
#define EPS 0.1f
#define CHUNK 160
#define NSPLIT ((KC + CHUNK - 1) / CHUNK)   // 63

// workspace layout in floats
#define WS_LOGITS 0
#define WS_W      (WS_LOGITS + B * KC)              // 80256
#define WS_BOOT   (WS_W + B * NROW * KC)            // + 8105856
// total = 8392960 floats = 33.6 MB

// ---------------- kernel 1: logits[b,k] ----------------
// one 64-lane wave per particle; 4 particles per 256-thread block
__global__ __launch_bounds__(256) void k_logits(
    const float* __restrict__ xt, const float* __restrict__ live_x0,
    const float* __restrict__ live_ll, const float* __restrict__ x0n,
    const float* __restrict__ lln, const float* __restrict__ ts_p,
    float* __restrict__ logits) {
  int b = blockIdx.y;
  int k = blockIdx.x * 4 + (threadIdx.x >> 6);
  int lane = threadIdx.x & 63;
  const float* src = (k < N_LIVE)
      ? (live_x0 + ((size_t)b * N_LIVE + k) * D)
      : (x0n + ((size_t)b * K_NEW + (k - N_LIVE)) * D);
  float4 v = ((const float4*)src)[lane];
  float4 c = ((const float4*)(xt + b * D))[lane];
  float dx = v.x - c.x, dy = v.y - c.y, dz = v.z - c.z, dw = v.w - c.w;
  float s = dx * dx + dy * dy + dz * dz + dw * dw;
#pragma unroll
  for (int off = 32; off; off >>= 1) s += __shfl_xor(s, off);
  if (lane == 0) {
    float ts = *ts_p;
    float out;
    if (k < N_LIVE)
      out = live_ll[(size_t)b * N_LIVE + k] - 0.5f * s / (ts * ts) - logf(ts);
    else
      out = lln[(size_t)b * K_NEW + (k - N_LIVE)];  // gaussian corr cancels exactly
    logits[(size_t)b * KC + k] = out;
  }
}

// ---------------- kernel 2: per-(n,b) softmax weight scatter ----------------
// one block per (n,b); n==100 is the identity row (plain softmax -> final score)
__global__ __launch_bounds__(256) void k_wbuild(
    const float* __restrict__ logits, const int* __restrict__ boot_idx,
    float* __restrict__ W) {
  __shared__ float wexp[KC];     // 40128 B
  __shared__ float sred[4];
  int wg = blockIdx.x;
  int b = wg & 7;
  int n = wg >> 3;               // 0..100
  int tid = threadIdx.x;
  const float* lg = logits + (size_t)b * KC;
  const int* row = boot_idx + ((size_t)n * B + b) * KC;  // only valid for n<100

  for (int i = tid; i < KC; i += 256) wexp[i] = 0.f;

  // pass A: row max (softmax stability)
  float lmax = -INFINITY;
  for (int k = tid; k < KC; k += 256) {
    int j = (n < NS) ? row[k] : k;
    lmax = fmaxf(lmax, lg[j]);
  }
#pragma unroll
  for (int off = 32; off; off >>= 1) lmax = fmaxf(lmax, __shfl_xor(lmax, off));
  if ((tid & 63) == 0) sred[tid >> 6] = lmax;
  __syncthreads();               // also orders wexp zeroing before atomics
  float M = fmaxf(fmaxf(sred[0], sred[1]), fmaxf(sred[2], sred[3]));
  __syncthreads();

  // pass B: exp + scatter-accumulate per original particle
  float lsum = 0.f;
  for (int k = tid; k < KC; k += 256) {
    int j = (n < NS) ? row[k] : k;
    float e = expf(lg[j] - M);
    atomicAdd(&wexp[j], e);      // ds_add_f32
    lsum += e;
  }
#pragma unroll
  for (int off = 32; off; off >>= 1) lsum += __shfl_xor(lsum, off);
  if ((tid & 63) == 0) sred[tid >> 6] = lsum;
  __syncthreads();               // all LDS atomics drained here
  float inv = 1.f / (sred[0] + sred[1] + sred[2] + sred[3]);

  float* wout = W + ((size_t)b * NROW + n) * KC;
  for (int i = tid; i < KC; i += 256) wout[i] = wexp[i] * inv;
}

// ---------------- kernel 3: boot[b] = W[b] @ X[b]  (fp32 vector GEMM) ----------------
// thread = output column d; 101 accumulators/thread; W loads are wave-uniform
// (scalar pipe) so VALU is pure FMA. k-split across blocks, atomicAdd combine.
__global__ __launch_bounds__(256) void k_gemm(
    const float* __restrict__ live_x0, const float* __restrict__ x0n,
    const float* __restrict__ W, float* __restrict__ boot) {
  int b = blockIdx.y;
  int k0 = blockIdx.x * CHUNK;
  int k1 = min(k0 + CHUNK, KC);
  int d = threadIdx.x;
  float acc[NROW];
#pragma unroll
  for (int n = 0; n < NROW; n++) acc[n] = 0.f;
  const float* Wb = W + (size_t)b * NROW * KC;
  const float* lx = live_x0 + (size_t)b * N_LIVE * D;
  const float* nx = x0n + (size_t)b * K_NEW * D;
  for (int k = k0; k < k1; k += 4) {
    float xv[4];
#pragma unroll
    for (int u = 0; u < 4; u++) {
      int kk = k + u;   // N_LIVE%4==0 and k0%4==0 -> no straddle inside a quad
      xv[u] = (kk < N_LIVE) ? lx[(size_t)kk * D + d]
                            : nx[(size_t)(kk - N_LIVE) * D + d];
    }
#pragma unroll
    for (int n = 0; n < NROW; n++) {
      const float4 w = *(const float4*)(Wb + (size_t)n * KC + k);
      acc[n] = fmaf(w.x, xv[0], acc[n]);
      acc[n] = fmaf(w.y, xv[1], acc[n]);
      acc[n] = fmaf(w.z, xv[2], acc[n]);
      acc[n] = fmaf(w.w, xv[3], acc[n]);
    }
  }
  float* ob = boot + (size_t)b * NROW * D + d;
#pragma unroll
  for (int n = 0; n < NROW; n++) atomicAdd(ob + (size_t)n * D, acc[n]);
}

// ---------------- kernel 4: std over bootstrap rows + epilogue ----------------
__global__ __launch_bounds__(256) void k_final(
    const float* __restrict__ boot, const float* __restrict__ xt,
    const float* __restrict__ ts_p, float* __restrict__ out) {
  int b = blockIdx.x;
  int d = threadIdx.x;
  float ts = *ts_p;
  const float* bb = boot + (size_t)b * NROW * D + d;
  float sum = 0.f;
  for (int n = 0; n < NS; n++) sum += bb[(size_t)n * D];
  float mean = sum / (float)NS;
  float vs = 0.f;
  for (int n = 0; n < NS; n++) { float t = bb[(size_t)n * D] - mean; vs += t * t; }
  float sigma_raw = sqrtf(vs / (float)(NS - 1));
  // std((x - xt)/ts) = std(x)/ts   (ts > 0); condition: sigma_v < EPS*ts
  bool ok = (sigma_raw / ts) < (EPS * ts);
  // score = (sum_k w*x - xt)/ts  since sum_k w == 1
  out[(size_t)b * D + d] = (bb[(size_t)NS * D] - xt[(size_t)b * D + d]) / ts;
  unsigned long long m = __ballot(ok);
  __shared__ int wok[4];
  if ((d & 63) == 0) wok[d >> 6] = (m == 0xFFFFFFFFFFFFFFFFull) ? 1 : 0;
  __syncthreads();
  if (d == 0) out[(size_t)B * D + b] = (wok[0] & wok[1] & wok[2] & wok[3]) ? 1.0f : 0.0f;
}

extern "C" void kernel_launch(void* const* d_in, const int* in_sizes, int n_in,
                              void* d_out, int out_size, void* d_ws, size_t ws_size,
                              hipStream_t stream) {
  const float* xt       = (const float*)d_in[0];
  const float* live_x0  = (const float*)d_in[1];
  const float* live_ll  = (const float*)d_in[2];
  const float* x0n      = (const float*)d_in[3];
  const float* lln      = (const float*)d_in[4];
  const float* ts_p     = (const float*)d_in[5];
  const int*   boot_idx = (const int*)d_in[6];
  float* out = (float*)d_out;
  float* ws  = (float*)d_ws;

  float* logits = ws + WS_LOGITS;
  float* W      = ws + WS_W;
  float* boot   = ws + WS_BOOT;

  // zero the GEMM accumulation buffer (ws is poisoned 0xAA before every call)
  hipMemsetAsync(boot, 0, (size_t)B * NROW * D * sizeof(float), stream);

  k_logits<<<dim3(KC / 4, B), 256, 0, stream>>>(xt, live_x0, live_ll, x0n, lln, ts_p, logits);
  k_wbuild<<<dim3(B * NROW), 256, 0, stream>>>(logits, boot_idx, W);
  k_gemm<<<dim3(NSPLIT, B), 256, 0, stream>>>(live_x0, x0n, W, boot);
  k_final<<<dim3(B), 256, 0, stream>>>(boot, xt, ts_p, out);
}

// Round 2
// 572.583 us; speedup vs baseline: 1.1379x; 1.1379x over previous
//
#include <hip/hip_runtime.h>
#include <math.h>

#define B 8
#define D 256
#define N_LIVE 10000
#define K_NEW 32
#define KC 10032
#define NS 100
#define NROW 101            // 100 bootstrap rows + 1 plain-softmax row (the score)
#define EPS 0.1f

// GEMM tiling: 3 row-tiles of NT=34 (covers 102 >= 101, last row clamped),
// k-split S=24 chunks of 420 (24*420 = 10080 >= 10032; 420 % 4 == 0)
#define NT 34
#define NTILES 3
#define KS 24
#define KCHUNK 420

// workspace layout in floats (total = 8392960 floats = 33.57 MB, same as r1)
#define WS_LOGITS 0
#define WS_W      (WS_LOGITS + B * KC)              // 80256
#define WS_BOOT   (WS_W + B * NROW * KC)            // + 8105856

// ---------------- kernel 1: logits[b,k] ----------------
// one 64-lane wave per particle; 4 particles per 256-thread block
__global__ __launch_bounds__(256) void k_logits(
    const float* __restrict__ xt, const float* __restrict__ live_x0,
    const float* __restrict__ live_ll, const float* __restrict__ x0n,
    const float* __restrict__ lln, const float* __restrict__ ts_p,
    float* __restrict__ logits) {
  int b = blockIdx.y;
  int k = blockIdx.x * 4 + (threadIdx.x >> 6);
  int lane = threadIdx.x & 63;
  const float* src = (k < N_LIVE)
      ? (live_x0 + ((size_t)b * N_LIVE + k) * D)
      : (x0n + ((size_t)b * K_NEW + (k - N_LIVE)) * D);
  float4 v = ((const float4*)src)[lane];
  float4 c = ((const float4*)(xt + b * D))[lane];
  float dx = v.x - c.x, dy = v.y - c.y, dz = v.z - c.z, dw = v.w - c.w;
  float s = dx * dx + dy * dy + dz * dz + dw * dw;
#pragma unroll
  for (int off = 32; off; off >>= 1) s += __shfl_xor(s, off);
  if (lane == 0) {
    float ts = *ts_p;
    float out;
    if (k < N_LIVE)
      out = live_ll[(size_t)b * N_LIVE + k] - 0.5f * s / (ts * ts) - logf(ts);
    else
      out = lln[(size_t)b * K_NEW + (k - N_LIVE)];  // gaussian corr cancels exactly
    logits[(size_t)b * KC + k] = out;
  }
}

// ---------------- kernel 2: per-(n,b) softmax weight scatter ----------------
// one block per (n,b); n==100 is the identity row (plain softmax -> final score).
// Stability max M = per-b GLOBAL max over logits (coalesced read): a valid upper
// bound for every resampled row (every row draws from this logit set), so
// exp(l-M) in (0,1], no overflow; softmax normalization makes M cancel exactly.
__global__ __launch_bounds__(256) void k_wbuild(
    const float* __restrict__ logits, const int* __restrict__ boot_idx,
    float* __restrict__ W) {
  __shared__ float wexp[KC];     // 40128 B
  __shared__ float sred[4];
  int wg = blockIdx.x;
  int b = wg & 7;
  int n = wg >> 3;               // 0..100
  int tid = threadIdx.x;
  const float* lg = logits + (size_t)b * KC;
  const int* row = boot_idx + ((size_t)n * B + b) * KC;  // only valid for n<100

  for (int i = tid; i < KC; i += 256) wexp[i] = 0.f;

  // pass A: per-b max (coalesced, no gather)
  float lmax = -INFINITY;
  for (int k = tid; k < KC; k += 256) lmax = fmaxf(lmax, lg[k]);
#pragma unroll
  for (int off = 32; off; off >>= 1) lmax = fmaxf(lmax, __shfl_xor(lmax, off));
  if ((tid & 63) == 0) sred[tid >> 6] = lmax;
  __syncthreads();               // also orders wexp zeroing before atomics
  float M = fmaxf(fmaxf(sred[0], sred[1]), fmaxf(sred[2], sred[3]));
  __syncthreads();

  // pass B: exp + scatter-accumulate per original particle
  float lsum = 0.f;
  for (int k = tid; k < KC; k += 256) {
    int j = (n < NS) ? row[k] : k;
    float e = expf(lg[j] - M);
    atomicAdd(&wexp[j], e);      // ds_add_f32
    lsum += e;
  }
#pragma unroll
  for (int off = 32; off; off >>= 1) lsum += __shfl_xor(lsum, off);
  if ((tid & 63) == 0) sred[tid >> 6] = lsum;
  __syncthreads();               // all LDS atomics drained here
  float inv = 1.f / (sred[0] + sred[1] + sred[2] + sred[3]);

  float* wout = W + ((size_t)b * NROW + n) * KC;
  for (int i = tid; i < KC; i += 256) wout[i] = wexp[i] * inv;
}

// ---------------- kernel 3: boot[b] = W[b] @ X[b]  (fp32 vector GEMM) ----------------
// thread = output column d. Row-tiled: NT=34 accumulators/thread -> stays in
// VGPRs (no AGPR shuffle, no spill). Block = (b, row-tile, k-chunk).
// W loads are wave-uniform -> scalar pipe; X loads coalesced (64 consecutive d).
__global__ __launch_bounds__(256, 4) void k_gemm(
    const float* __restrict__ live_x0, const float* __restrict__ x0n,
    const float* __restrict__ W, float* __restrict__ boot) {
  int b = blockIdx.y;
  int nt = blockIdx.x % NTILES;
  int s  = blockIdx.x / NTILES;
  int n0 = nt * NT;
  int k0 = s * KCHUNK;
  int k1 = min(k0 + KCHUNK, KC);
  int d = threadIdx.x;

  float acc[NT];
#pragma unroll
  for (int i = 0; i < NT; i++) acc[i] = 0.f;

  const float* Wb = W + (size_t)b * NROW * KC;
  const float* lx = live_x0 + (size_t)b * N_LIVE * D;
  const float* nx = x0n + (size_t)b * K_NEW * D;

  for (int k = k0; k < k1; k += 4) {
    float xv[4];
#pragma unroll
    for (int u = 0; u < 4; u++) {
      int kk = k + u;   // KCHUNK%4==0 and N_LIVE%4==0 -> no straddle inside a quad
      xv[u] = (kk < N_LIVE) ? lx[(size_t)kk * D + d]
                            : nx[(size_t)(kk - N_LIVE) * D + d];
    }
#pragma unroll
    for (int i = 0; i < NT; i++) {
      int n = n0 + i;
      int nc = (n <= 100) ? n : 100;               // clamp: row-102 pad does dup work
      const float4 w = *(const float4*)(Wb + (size_t)nc * KC + k);
      acc[i] = fmaf(w.x, xv[0], acc[i]);
      acc[i] = fmaf(w.y, xv[1], acc[i]);
      acc[i] = fmaf(w.z, xv[2], acc[i]);
      acc[i] = fmaf(w.w, xv[3], acc[i]);
    }
  }
  float* ob = boot + ((size_t)b * NROW + n0) * D + d;
#pragma unroll
  for (int i = 0; i < NT; i++)
    if (n0 + i <= 100) atomicAdd(ob + (size_t)i * D, acc[i]);  // pad row dropped
}

// ---------------- kernel 4: std over bootstrap rows + epilogue ----------------
__global__ __launch_bounds__(256) void k_final(
    const float* __restrict__ boot, const float* __restrict__ xt,
    const float* __restrict__ ts_p, float* __restrict__ out) {
  int b = blockIdx.x;
  int d = threadIdx.x;
  float ts = *ts_p;
  const float* bb = boot + (size_t)b * NROW * D + d;
  float sum = 0.f;
  for (int n = 0; n < NS; n++) sum += bb[(size_t)n * D];
  float mean = sum / (float)NS;
  float vs = 0.f;
  for (int n = 0; n < NS; n++) { float t = bb[(size_t)n * D] - mean; vs += t * t; }
  float sigma_raw = sqrtf(vs / (float)(NS - 1));
  // std((x - xt)/ts) = std(x)/ts   (ts > 0); condition: sigma_v < EPS*ts
  bool ok = (sigma_raw / ts) < (EPS * ts);
  // score = (sum_k w*x - xt)/ts  since sum_k w == 1
  out[(size_t)b * D + d] = (bb[(size_t)NS * D] - xt[(size_t)b * D + d]) / ts;
  unsigned long long m = __ballot(ok);
  __shared__ int wok[4];
  if ((d & 63) == 0) wok[d >> 6] = (m == 0xFFFFFFFFFFFFFFFFull) ? 1 : 0;
  __syncthreads();
  if (d == 0) out[(size_t)B * D + b] = (wok[0] & wok[1] & wok[2] & wok[3]) ? 1.0f : 0.0f;
}

extern "C" void kernel_launch(void* const* d_in, const int* in_sizes, int n_in,
                              void* d_out, int out_size, void* d_ws, size_t ws_size,
                              hipStream_t stream) {
  const float* xt       = (const float*)d_in[0];
  const float* live_x0  = (const float*)d_in[1];
  const float* live_ll  = (const float*)d_in[2];
  const float* x0n      = (const float*)d_in[3];
  const float* lln      = (const float*)d_in[4];
  const float* ts_p     = (const float*)d_in[5];
  const int*   boot_idx = (const int*)d_in[6];
  float* out = (float*)d_out;
  float* ws  = (float*)d_ws;

  float* logits = ws + WS_LOGITS;
  float* W      = ws + WS_W;
  float* boot   = ws + WS_BOOT;

  // zero the GEMM accumulation buffer (ws is poisoned 0xAA before every call)
  hipMemsetAsync(boot, 0, (size_t)B * NROW * D * sizeof(float), stream);

  k_logits<<<dim3(KC / 4, B), 256, 0, stream>>>(xt, live_x0, live_ll, x0n, lln, ts_p, logits);
  k_wbuild<<<dim3(B * NROW), 256, 0, stream>>>(logits, boot_idx, W);
  k_gemm<<<dim3(NTILES * KS, B), 256, 0, stream>>>(live_x0, x0n, W, boot);
  k_final<<<dim3(B), 256, 0, stream>>>(boot, xt, ts_p, out);
}

// Round 3
// 189.387 us; speedup vs baseline: 3.4403x; 3.0234x over previous
//
#include <hip/hip_runtime.h>
#include <math.h>

#define B 8
#define D 256
#define N_LIVE 10000
#define K_NEW 32
#define KC 10032
#define NS 100
#define NROW 101            // 100 bootstrap rows + 1 plain-softmax row (the score)
#define EPS 0.1f
#define CAP 1024            // active-set capacity (expected ~75 per b)
#define ACT_CUT 87.0f       // exp(-87)=1.65e-38: anything below underflows fp32 anyway

// workspace layout in floats (total ~1.53 MB; ws >= 33.6 MB known-good)
#define WS_LOGITS 0                          // B*KC
#define WS_ACTE   (WS_LOGITS + B * KC)       // B*CAP floats: e_j = exp(l-M)
#define WS_ACTI   (WS_ACTE + B * CAP)        // B*CAP ints: particle index j
#define WS_CNT    (WS_ACTI + B * CAP)        // B ints: active count
#define WS_LUT    (WS_CNT + 8)               // B*KC ints: j -> active slot+1 (0=inactive)
#define WS_BOOT   (WS_LUT + B * KC)          // B*NROW*D floats

// ---------------- kernel 1: logits[b,k] ----------------
// one 64-lane wave per particle; 4 particles per 256-thread block
__global__ __launch_bounds__(256) void k_logits(
    const float* __restrict__ xt, const float* __restrict__ live_x0,
    const float* __restrict__ live_ll, const float* __restrict__ x0n,
    const float* __restrict__ lln, const float* __restrict__ ts_p,
    float* __restrict__ logits) {
  int b = blockIdx.y;
  int k = blockIdx.x * 4 + (threadIdx.x >> 6);
  int lane = threadIdx.x & 63;
  const float* src = (k < N_LIVE)
      ? (live_x0 + ((size_t)b * N_LIVE + k) * D)
      : (x0n + ((size_t)b * K_NEW + (k - N_LIVE)) * D);
  float4 v = ((const float4*)src)[lane];
  float4 c = ((const float4*)(xt + b * D))[lane];
  float dx = v.x - c.x, dy = v.y - c.y, dz = v.z - c.z, dw = v.w - c.w;
  float s = dx * dx + dy * dy + dz * dz + dw * dw;
#pragma unroll
  for (int off = 32; off; off >>= 1) s += __shfl_xor(s, off);
  if (lane == 0) {
    float ts = *ts_p;
    float out;
    if (k < N_LIVE)
      out = live_ll[(size_t)b * N_LIVE + k] - 0.5f * s / (ts * ts) - logf(ts);
    else
      out = lln[(size_t)b * K_NEW + (k - N_LIVE)];  // gaussian corr cancels exactly
    logits[(size_t)b * KC + k] = out;
  }
}

// ---------------- kernel 2: per-b max + active-set selection ----------------
// One 1024-thread block per b. Active = logit within ACT_CUT of the per-b max;
// everything else has exp(l-M) below fp32-normal range -> weight 0 in fp32.
__global__ __launch_bounds__(1024) void k_maxsel(
    const float* __restrict__ logits, float* __restrict__ act_e,
    int* __restrict__ act_idx, int* __restrict__ act_cnt, int* __restrict__ lut) {
  int b = blockIdx.x;
  int tid = threadIdx.x;
  const float* lg = logits + (size_t)b * KC;
  __shared__ float smax[16];
  __shared__ int scnt;
  float m = -INFINITY;
  for (int k = tid; k < KC; k += 1024) m = fmaxf(m, lg[k]);
#pragma unroll
  for (int off = 32; off; off >>= 1) m = fmaxf(m, __shfl_xor(m, off));
  if ((tid & 63) == 0) smax[tid >> 6] = m;
  if (tid == 0) scnt = 0;
  __syncthreads();
  float M = smax[0];
#pragma unroll
  for (int i = 1; i < 16; i++) M = fmaxf(M, smax[i]);

  for (int k = tid; k < KC; k += 1024) {
    float l = lg[k];
    int v = 0;
    if (l > M - ACT_CUT) {
      int pos = atomicAdd(&scnt, 1);
      if (pos < CAP) {
        act_e[b * CAP + pos] = expf(l - M);
        act_idx[b * CAP + pos] = k;
        v = pos + 1;
      }
    }
    lut[(size_t)b * KC + k] = v;
  }
  __syncthreads();
  if (tid == 0) act_cnt[b] = min(scnt, CAP);
}

// ---------------- kernel 3: fused count + sparse weighted sum ----------------
// One block per (n,b). Counts occurrences of active particles in the bootstrap
// row (LDS atomics, ~75 hits per 10032 draws), then boot[n,b,d] =
// sum_j c_j e_j x[j,d] / sum_j c_j e_j over the ~50 nonzero actives.
// n==100 is the identity row (plain softmax -> final score).
__global__ __launch_bounds__(256) void k_boot(
    const float* __restrict__ live_x0, const float* __restrict__ x0n,
    const float* __restrict__ act_e, const int* __restrict__ act_idx,
    const int* __restrict__ act_cnt, const int* __restrict__ lut,
    const int* __restrict__ boot_idx, float* __restrict__ boot) {
  int n = blockIdx.x;   // 0..100
  int b = blockIdx.y;
  int tid = threadIdx.x;
  __shared__ int cnt[CAP];
  __shared__ float wval[CAP];
  __shared__ int widx[CAP];
  __shared__ int snnz;
  __shared__ float sden[4];
  int A = act_cnt[b];
  for (int i = tid; i < A; i += 256) cnt[i] = 0;
  if (tid == 0) snnz = 0;
  __syncthreads();

  if (n < NS) {
    const int4* row = (const int4*)(boot_idx + ((size_t)n * B + b) * KC);
    const int* lutb = lut + (size_t)b * KC;
    for (int k = tid; k < KC / 4; k += 256) {   // KC%4==0
      int4 v = row[k];
      int t;
      t = lutb[v.x]; if (t) atomicAdd(&cnt[t - 1], 1);
      t = lutb[v.y]; if (t) atomicAdd(&cnt[t - 1], 1);
      t = lutb[v.z]; if (t) atomicAdd(&cnt[t - 1], 1);
      t = lutb[v.w]; if (t) atomicAdd(&cnt[t - 1], 1);
    }
  } else {
    for (int i = tid; i < A; i += 256) cnt[i] = 1;
  }
  __syncthreads();

  // compact nonzero actives + denominator
  float dpart = 0.f;
  for (int i = tid; i < A; i += 256) {
    int c = cnt[i];
    if (c) {
      float w = (float)c * act_e[b * CAP + i];
      int pos = atomicAdd(&snnz, 1);
      wval[pos] = w;
      widx[pos] = act_idx[b * CAP + i];
      dpart += w;
    }
  }
#pragma unroll
  for (int off = 32; off; off >>= 1) dpart += __shfl_xor(dpart, off);
  if ((tid & 63) == 0) sden[tid >> 6] = dpart;
  __syncthreads();
  float inv = 1.f / (sden[0] + sden[1] + sden[2] + sden[3]);
  int nnz = snnz;

  const float* lx = live_x0 + (size_t)b * N_LIVE * D;
  const float* nx = x0n + (size_t)b * K_NEW * D;
  float acc = 0.f;
  for (int p = 0; p < nnz; p++) {
    int j = widx[p];
    const float* xr = (j < N_LIVE) ? (lx + (size_t)j * D)
                                   : (nx + (size_t)(j - N_LIVE) * D);
    acc = fmaf(wval[p], xr[tid], acc);   // coalesced 256B line per wave, L3-hot
  }
  boot[((size_t)b * NROW + n) * D + tid] = acc * inv;
}

// ---------------- kernel 4: std over bootstrap rows + epilogue ----------------
__global__ __launch_bounds__(256) void k_final(
    const float* __restrict__ boot, const float* __restrict__ xt,
    const float* __restrict__ ts_p, float* __restrict__ out) {
  int b = blockIdx.x;
  int d = threadIdx.x;
  float ts = *ts_p;
  const float* bb = boot + (size_t)b * NROW * D + d;
  float sum = 0.f;
  for (int n = 0; n < NS; n++) sum += bb[(size_t)n * D];
  float mean = sum / (float)NS;
  float vs = 0.f;
  for (int n = 0; n < NS; n++) { float t = bb[(size_t)n * D] - mean; vs += t * t; }
  float sigma_raw = sqrtf(vs / (float)(NS - 1));
  // std((x - xt)/ts) = std(x)/ts   (ts > 0); condition: sigma_v < EPS*ts
  bool ok = (sigma_raw / ts) < (EPS * ts);
  // score = (sum_k w*x - xt)/ts  since sum_k w == 1
  out[(size_t)b * D + d] = (bb[(size_t)NS * D] - xt[(size_t)b * D + d]) / ts;
  unsigned long long m = __ballot(ok);
  __shared__ int wok[4];
  if ((d & 63) == 0) wok[d >> 6] = (m == 0xFFFFFFFFFFFFFFFFull) ? 1 : 0;
  __syncthreads();
  if (d == 0) out[(size_t)B * D + b] = (wok[0] & wok[1] & wok[2] & wok[3]) ? 1.0f : 0.0f;
}

extern "C" void kernel_launch(void* const* d_in, const int* in_sizes, int n_in,
                              void* d_out, int out_size, void* d_ws, size_t ws_size,
                              hipStream_t stream) {
  const float* xt       = (const float*)d_in[0];
  const float* live_x0  = (const float*)d_in[1];
  const float* live_ll  = (const float*)d_in[2];
  const float* x0n      = (const float*)d_in[3];
  const float* lln      = (const float*)d_in[4];
  const float* ts_p     = (const float*)d_in[5];
  const int*   boot_idx = (const int*)d_in[6];
  float* out = (float*)d_out;
  float* ws  = (float*)d_ws;

  float* logits  = ws + WS_LOGITS;
  float* act_e   = ws + WS_ACTE;
  int*   act_idx = (int*)(ws + WS_ACTI);
  int*   act_cnt = (int*)(ws + WS_CNT);
  int*   lut     = (int*)(ws + WS_LUT);
  float* boot    = ws + WS_BOOT;

  k_logits<<<dim3(KC / 4, B), 256, 0, stream>>>(xt, live_x0, live_ll, x0n, lln, ts_p, logits);
  k_maxsel<<<dim3(B), 1024, 0, stream>>>(logits, act_e, act_idx, act_cnt, lut);
  k_boot<<<dim3(NROW, B), 256, 0, stream>>>(live_x0, x0n, act_e, act_idx, act_cnt, lut, boot_idx, boot);
  k_final<<<dim3(B), 256, 0, stream>>>(boot, xt, ts_p, out);
}